// Round 2
// baseline (8549.495 us; speedup 1.0000x reference)
//
#include <hip/hip_runtime.h>
#include <hip/hip_bf16.h>
#include <cstdint>

#define B_  2
#define CK_ 64
#define NM_ 32768
#define NQ_ 4096
#define CV_ 256
#define K_  20
#define SEG_ 16      // m-segments for score kernel parallelism

typedef unsigned short ushort_t;
typedef unsigned int uint_t;
typedef float f32x4 __attribute__((ext_vector_type(4)));
typedef float f32x2 __attribute__((ext_vector_type(2)));
typedef short short8v __attribute__((ext_vector_type(8)));

__device__ __forceinline__ ushort_t f2bf_rn(float f) {
  uint_t x = __float_as_uint(f);
  uint_t r = x + 0x7FFFu + ((x >> 16) & 1u);
  return (ushort_t)(r >> 16);
}
__device__ __forceinline__ float bf2f(ushort_t u) {
  return __uint_as_float(((uint_t)u) << 16);
}

// ------------------------------------------------------------------
// prep_mk: mk[b][c][m] fp32 -> mkh/mkl[b][m][c] bf16 split, ans = 0.125*||mk||^2
__global__ __launch_bounds__(256) void prep_mk(const float* __restrict__ mk,
                                               ushort_t* __restrict__ mkh,
                                               ushort_t* __restrict__ mkl,
                                               float* __restrict__ ans) {
  int i = blockIdx.x * 256 + threadIdx.x;      // b*NM + m
  int b = i >> 15, m = i & (NM_ - 1);
  const float* src = mk + (size_t)b * CK_ * NM_ + m;
  ushort_t* dh = mkh + (size_t)i * CK_;
  ushort_t* dl = mkl + (size_t)i * CK_;
  float s = 0.f;
  #pragma unroll
  for (int c8 = 0; c8 < 8; ++c8) {
    ushort_t hh[8], ll[8];
    #pragma unroll
    for (int j = 0; j < 8; ++j) {
      float v = src[(size_t)(c8 * 8 + j) * NM_];
      s = fmaf(v, v, s);
      ushort_t h = f2bf_rn(v);
      hh[j] = h;
      ll[j] = f2bf_rn(v - bf2f(h));
    }
    *reinterpret_cast<short8v*>(dh + c8 * 8) = *reinterpret_cast<short8v*>(hh);
    *reinterpret_cast<short8v*>(dl + c8 * 8) = *reinterpret_cast<short8v*>(ll);
  }
  ans[i] = 0.125f * s;
}

// prep_qk: qk[b][c][q] fp32 -> qkh/qkl[b][q][c] bf16 split of 0.25*qk
__global__ __launch_bounds__(256) void prep_qk(const float* __restrict__ qk,
                                               ushort_t* __restrict__ qkh,
                                               ushort_t* __restrict__ qkl) {
  int i = blockIdx.x * 256 + threadIdx.x;      // b*NQ + q
  int b = i >> 12, q = i & (NQ_ - 1);
  const float* src = qk + (size_t)b * CK_ * NQ_ + q;
  ushort_t* dh = qkh + (size_t)i * CK_;
  ushort_t* dl = qkl + (size_t)i * CK_;
  #pragma unroll
  for (int c8 = 0; c8 < 8; ++c8) {
    ushort_t hh[8], ll[8];
    #pragma unroll
    for (int j = 0; j < 8; ++j) {
      float v = 0.25f * src[(size_t)(c8 * 8 + j) * NQ_];
      ushort_t h = f2bf_rn(v);
      hh[j] = h;
      ll[j] = f2bf_rn(v - bf2f(h));
    }
    *reinterpret_cast<short8v*>(dh + c8 * 8) = *reinterpret_cast<short8v*>(hh);
    *reinterpret_cast<short8v*>(dl + c8 * 8) = *reinterpret_cast<short8v*>(ll);
  }
}

// ------------------------------------------------------------------
// transpose_mv: mv[b][c][m] fp32 -> mvt[b][m][c] bf16
__global__ __launch_bounds__(256) void transpose_mv(const float* __restrict__ mv0,
                                                    const float* __restrict__ mv1,
                                                    ushort_t* __restrict__ mvt0,
                                                    ushort_t* __restrict__ mvt1) {
  __shared__ float tl[64][33];
  const int zz = blockIdx.z;                   // bank + 2*b
  const int bank = zz & 1, b = zz >> 1;
  const float* src = (bank ? mv1 : mv0) + (size_t)b * CV_ * NM_;
  ushort_t*    dst = (bank ? mvt1 : mvt0) + (size_t)b * NM_ * CV_;
  const int m0 = blockIdx.x * 32, c0 = blockIdx.y * 64;
  const int t = threadIdx.x;
  #pragma unroll
  for (int i = 0; i < 8; ++i) {
    int f = t + 256 * i;
    int c = f >> 5, ml = f & 31;
    tl[c][ml] = src[(size_t)(c0 + c) * NM_ + m0 + ml];
  }
  __syncthreads();
  int m = t >> 3, c8 = t & 7;
  ushort_t pack[8];
  #pragma unroll
  for (int j = 0; j < 8; ++j) pack[j] = f2bf_rn(tl[c8 * 8 + j][m]);
  *reinterpret_cast<short8v*>(dst + (size_t)(m0 + m) * CV_ + c0 + c8 * 8) =
      *reinterpret_cast<short8v*>(pack);
}

// ------------------------------------------------------------------
// score + top-20 via split-bf16 MFMA.
// block = 256 thr (4 waves), owns 256 queries x one m-segment (NM/SEG entries).
// grid: (NQ/256, SEG, B)
#define LDSQ 34   // padded floats per query row (32 scores + 2)

__global__ __launch_bounds__(256, 2) void score_topk_mfma(
    const ushort_t* __restrict__ mkh, const ushort_t* __restrict__ mkl,
    const ushort_t* __restrict__ qkh, const ushort_t* __restrict__ qkl,
    const float* __restrict__ ans,
    float* __restrict__ pvals, int* __restrict__ pidx) {
  __shared__ float S_lds[256 * LDSQ];
  const int t = threadIdx.x;
  const int b = blockIdx.z, seg = blockIdx.y, qblk = blockIdx.x;
  const int S = gridDim.y;
  const int mseg = NM_ / S;
  const int chunks = mseg >> 5;
  const int w = t >> 6, l = t & 63;
  const int lr = l & 15, lg = l >> 4;
  const int mseg0 = seg * mseg;

  // --- B fragments (qk hi/lo), persistent in registers ---
  short8v bh[4][2], bl[4][2];
  {
    const size_t qrow = (size_t)b * NQ_ + qblk * 256 + w * 64 + lr;
    #pragma unroll
    for (int qt = 0; qt < 4; ++qt) {
      const size_t base = ((qrow + qt * 16) << 6) + (lg << 3);
      bh[qt][0] = *reinterpret_cast<const short8v*>(qkh + base);
      bh[qt][1] = *reinterpret_cast<const short8v*>(qkh + base + 32);
      bl[qt][0] = *reinterpret_cast<const short8v*>(qkl + base);
      bl[qt][1] = *reinterpret_cast<const short8v*>(qkl + base + 32);
    }
  }

  // --- per-thread top-K state (sorted desc) + 4-deep candidate stack ---
  float vals[K_]; int idxs[K_];
  #pragma unroll
  for (int j = 0; j < K_; ++j) { vals[j] = -3.4e38f; idxs[j] = 0; }
  float thr = -3.4e38f;
  float sk0 = 0, sk1 = 0, sk2 = 0, sk3 = 0;
  int km0 = 0, km1 = 0, km2 = 0, km3 = 0, cnt = 0;

  auto ins = [&](float s, int m) {
    if (s > vals[K_ - 1]) {
      vals[K_ - 1] = s; idxs[K_ - 1] = m;
      #pragma unroll
      for (int j = K_ - 1; j > 0; --j) {
        if (vals[j] > vals[j - 1]) {
          float tv = vals[j]; vals[j] = vals[j - 1]; vals[j - 1] = tv;
          int   ti = idxs[j]; idxs[j] = idxs[j - 1]; idxs[j - 1] = ti;
        }
      }
    }
  };
  auto push = [&](float s, int m) {
    if (s > thr) {
      if (cnt == 0)      { sk0 = s; km0 = m; }
      else if (cnt == 1) { sk1 = s; km1 = m; }
      else if (cnt == 2) { sk2 = s; km2 = m; }
      else               { sk3 = s; km3 = m; }
      ++cnt;
      if (cnt == 4) {
        ins(sk0, km0); ins(sk1, km1); ins(sk2, km2); ins(sk3, km3);
        cnt = 0; thr = vals[K_ - 1];
      }
    }
  };
  auto flush = [&]() {
    if (cnt > 0) ins(sk0, km0);
    if (cnt > 1) ins(sk1, km1);
    if (cnt > 2) ins(sk2, km2);
    cnt = 0; thr = vals[K_ - 1];
  };
  auto scan = [&](int chp) {
    const float* row = &S_lds[t * LDSQ];
    const int mb = mseg0 + (chp << 5);
    #pragma unroll 4
    for (int j = 0; j < 16; ++j) {
      f32x2 sv = *reinterpret_cast<const f32x2*>(row + 2 * j);
      push(sv[0], mb + 2 * j);
      push(sv[1], mb + 2 * j + 1);
    }
    if (__any(cnt >= 2)) flush();
  };

  for (int ch = 0; ch < chunks; ++ch) {
    const int m0 = mseg0 + (ch << 5);
    // ---- MFMA phase: 32 m x 64 q per wave ----
    f32x4 acc[2][4];
    #pragma unroll
    for (int mt = 0; mt < 2; ++mt)
      #pragma unroll
      for (int qt = 0; qt < 4; ++qt) acc[mt][qt] = 0.f;

    f32x4 an4[2];
    an4[0] = *reinterpret_cast<const f32x4*>(ans + (size_t)b * NM_ + m0 + (lg << 2));
    an4[1] = *reinterpret_cast<const f32x4*>(ans + (size_t)b * NM_ + m0 + 16 + (lg << 2));

    #pragma unroll
    for (int mt = 0; mt < 2; ++mt) {
      const size_t arow = (((size_t)b * NM_ + m0 + mt * 16 + lr) << 6) + (lg << 3);
      short8v ah0 = *reinterpret_cast<const short8v*>(mkh + arow);
      short8v ah1 = *reinterpret_cast<const short8v*>(mkh + arow + 32);
      short8v al0 = *reinterpret_cast<const short8v*>(mkl + arow);
      short8v al1 = *reinterpret_cast<const short8v*>(mkl + arow + 32);
      #pragma unroll
      for (int qt = 0; qt < 4; ++qt)
        acc[mt][qt] = __builtin_amdgcn_mfma_f32_16x16x32_bf16(ah0, bh[qt][0], acc[mt][qt], 0, 0, 0);
      #pragma unroll
      for (int qt = 0; qt < 4; ++qt)
        acc[mt][qt] = __builtin_amdgcn_mfma_f32_16x16x32_bf16(ah1, bh[qt][1], acc[mt][qt], 0, 0, 0);
      #pragma unroll
      for (int qt = 0; qt < 4; ++qt)
        acc[mt][qt] = __builtin_amdgcn_mfma_f32_16x16x32_bf16(ah0, bl[qt][0], acc[mt][qt], 0, 0, 0);
      #pragma unroll
      for (int qt = 0; qt < 4; ++qt)
        acc[mt][qt] = __builtin_amdgcn_mfma_f32_16x16x32_bf16(ah1, bl[qt][1], acc[mt][qt], 0, 0, 0);
      #pragma unroll
      for (int qt = 0; qt < 4; ++qt)
        acc[mt][qt] = __builtin_amdgcn_mfma_f32_16x16x32_bf16(al0, bh[qt][0], acc[mt][qt], 0, 0, 0);
      #pragma unroll
      for (int qt = 0; qt < 4; ++qt)
        acc[mt][qt] = __builtin_amdgcn_mfma_f32_16x16x32_bf16(al1, bh[qt][1], acc[mt][qt], 0, 0, 0);
    }

    // ---- scan previous chunk while MFMAs drain ----
    if (ch > 0) scan(ch - 1);
    __syncthreads();

    // ---- write scores: s = acc - 0.125*||mk||^2 ----
    #pragma unroll
    for (int mt = 0; mt < 2; ++mt) {
      #pragma unroll
      for (int qt = 0; qt < 4; ++qt) {
        f32x4 sv = acc[mt][qt] - an4[mt];
        const int qrow_l = (w << 6) + (qt << 4) + lr;
        float* p = &S_lds[qrow_l * LDSQ + (mt << 4) + (lg << 2)];
        f32x2 a = {sv[0], sv[1]}, c = {sv[2], sv[3]};
        *reinterpret_cast<f32x2*>(p) = a;
        *reinterpret_cast<f32x2*>(p + 2) = c;
      }
    }
    __syncthreads();
  }
  scan(chunks - 1);
  flush();

  const int q = (qblk << 8) + t;
  #pragma unroll
  for (int j = 0; j < K_; ++j) {
    size_t o = ((size_t)((b * S + seg) * K_ + j) << 12) + q;
    pvals[o] = vals[j]; pidx[o] = idxs[j];
  }
}

// ------------------------------------------------------------------
// merge segments + softmax
__global__ __launch_bounds__(256) void merge_kernel(const float* __restrict__ pvals,
                                                    const int* __restrict__ pidx,
                                                    float* __restrict__ fw,
                                                    int* __restrict__ fidx, int S) {
  int i = blockIdx.x * 256 + threadIdx.x;      // 0 .. B*NQ
  int b = i >> 12, q = i & (NQ_ - 1);

  float vals[K_]; int idxs[K_];
  #pragma unroll
  for (int j = 0; j < K_; ++j) { vals[j] = -3.4e38f; idxs[j] = 0; }

  for (int seg = 0; seg < S; ++seg) {
    #pragma unroll
    for (int j = 0; j < K_; ++j) {
      size_t o = (size_t)((b * S + seg) * K_ + j) * NQ_ + q;
      float v = pvals[o];
      if (v > vals[K_ - 1]) {
        int m = pidx[o];
        vals[K_ - 1] = v; idxs[K_ - 1] = m;
        #pragma unroll
        for (int jj = K_ - 1; jj > 0; --jj) {
          if (vals[jj] > vals[jj - 1]) {
            float tv = vals[jj]; vals[jj] = vals[jj - 1]; vals[jj - 1] = tv;
            int   ti = idxs[jj]; idxs[jj] = idxs[jj - 1]; idxs[jj - 1] = ti;
          }
        }
      }
    }
  }

  float mx = vals[0];
  float w[K_]; float sum = 0.f;
  #pragma unroll
  for (int j = 0; j < K_; ++j) { w[j] = expf(vals[j] - mx); sum += w[j]; }
  float inv = 1.f / sum;
  #pragma unroll
  for (int j = 0; j < K_; ++j) {
    size_t o = (size_t)(b * K_ + j) * NQ_ + q;
    fw[o] = w[j] * inv; fidx[o] = idxs[j];
  }
}

// ------------------------------------------------------------------
// sparse readout from bf16 transposed mv: thread handles 2 channels, 8 queries
__global__ __launch_bounds__(256) void readout_bf16(const ushort_t* __restrict__ mvt0,
                                                    const ushort_t* __restrict__ mvt1,
                                                    const float* __restrict__ fw,
                                                    const int* __restrict__ fidx,
                                                    float* __restrict__ out) {
  __shared__ float mw[16][K_];
  __shared__ int   mi[16][K_];
  __shared__ float ob0[256][17];
  __shared__ float ob1[256][17];
  const int t = threadIdx.x;
  const int b = blockIdx.y;
  const int q0 = blockIdx.x * 16;

  for (int i = t; i < 16 * K_; i += 256) {
    int qp = i / K_, k = i % K_;
    size_t o = (size_t)(b * K_ + k) * NQ_ + q0 + qp;
    mw[qp][k] = fw[o];
    mi[qp][k] = fidx[o];
  }
  __syncthreads();

  const int c2 = (t & 127) * 2, hq = t >> 7;
  for (int qp = hq * 8; qp < hq * 8 + 8; ++qp) {
    float a00 = 0.f, a01 = 0.f, a10 = 0.f, a11 = 0.f;
    #pragma unroll 5
    for (int k = 0; k < K_; ++k) {
      int m = mi[qp][k]; float ww = mw[qp][k];
      size_t o = ((size_t)(b * NM_ + m) << 8) + c2;   // *CV_
      uint_t v0 = *reinterpret_cast<const uint_t*>(mvt0 + o);
      uint_t v1 = *reinterpret_cast<const uint_t*>(mvt1 + o);
      a00 = fmaf(ww, __uint_as_float(v0 << 16), a00);
      a01 = fmaf(ww, __uint_as_float(v0 & 0xFFFF0000u), a01);
      a10 = fmaf(ww, __uint_as_float(v1 << 16), a10);
      a11 = fmaf(ww, __uint_as_float(v1 & 0xFFFF0000u), a11);
    }
    ob0[c2][qp] = a00; ob0[c2 + 1][qp] = a01;
    ob1[c2][qp] = a10; ob1[c2 + 1][qp] = a11;
  }
  __syncthreads();

  float* out0 = out + (size_t)b * CV_ * NQ_;
  float* out1 = out + (size_t)B_ * CV_ * NQ_ + (size_t)b * CV_ * NQ_;
  for (int i = t; i < 256 * 16; i += 256) {
    int c = i >> 4, qp = i & 15;
    out0[(size_t)c * NQ_ + q0 + qp] = ob0[c][qp];
    out1[(size_t)c * NQ_ + q0 + qp] = ob1[c][qp];
  }
}

// fallback readout from original fp32 layout (no transpose workspace)
__global__ __launch_bounds__(256) void readout_f32(const float* __restrict__ v0src,
                                                   const float* __restrict__ v1src,
                                                   const float* __restrict__ fw,
                                                   const int* __restrict__ fidx,
                                                   float* __restrict__ out) {
  __shared__ float mw[16][K_];
  __shared__ int   mi[16][K_];
  __shared__ float ob0[256][17];
  __shared__ float ob1[256][17];
  const int t = threadIdx.x;
  const int b = blockIdx.y;
  const int q0 = blockIdx.x * 16;

  for (int i = t; i < 16 * K_; i += 256) {
    int qp = i / K_, k = i % K_;
    size_t o = (size_t)(b * K_ + k) * NQ_ + q0 + qp;
    mw[qp][k] = fw[o];
    mi[qp][k] = fidx[o];
  }
  __syncthreads();

  for (int qp = 0; qp < 16; ++qp) {
    float a0 = 0.f, a1 = 0.f;
    #pragma unroll 5
    for (int k = 0; k < K_; ++k) {
      int m = mi[qp][k]; float ww = mw[qp][k];
      size_t o = (size_t)b * CV_ * NM_ + (size_t)t * NM_ + m;
      a0 = fmaf(ww, v0src[o], a0);
      a1 = fmaf(ww, v1src[o], a1);
    }
    ob0[t][qp] = a0; ob1[t][qp] = a1;
  }
  __syncthreads();

  float* out0 = out + (size_t)b * CV_ * NQ_;
  float* out1 = out + (size_t)B_ * CV_ * NQ_ + (size_t)b * CV_ * NQ_;
  for (int i = t; i < 256 * 16; i += 256) {
    int c = i >> 4, qp = i & 15;
    out0[(size_t)c * NQ_ + q0 + qp] = ob0[c][qp];
    out1[(size_t)c * NQ_ + q0 + qp] = ob1[c][qp];
  }
}

// ------------------------------------------------------------------
extern "C" void kernel_launch(void* const* d_in, const int* in_sizes, int n_in,
                              void* d_out, int out_size, void* d_ws, size_t ws_size,
                              hipStream_t stream) {
  (void)in_sizes; (void)n_in; (void)out_size;
  const float* mk  = (const float*)d_in[0];
  const float* qk  = (const float*)d_in[1];
  const float* mv0 = (const float*)d_in[2];
  const float* mv1 = (const float*)d_in[3];
  float* out = (float*)d_out;

  auto al = [](size_t x) { return (x + 255) & ~(size_t)255; };
  const size_t mkB  = (size_t)B_ * NM_ * CK_ * 2;   // bf16
  const size_t qkB  = (size_t)B_ * NQ_ * CK_ * 2;
  const size_t anB  = (size_t)B_ * NM_ * 4;
  const size_t prtB = (size_t)B_ * SEG_ * K_ * NQ_ * 4;
  const size_t finB = (size_t)B_ * K_ * NQ_ * 4;
  const size_t tpB  = (size_t)B_ * NM_ * CV_ * 2;   // bf16

  const size_t core = 2 * al(mkB) + 2 * al(qkB) + al(anB) + 2 * al(prtB) + 2 * al(finB);
  const bool tp = ws_size >= core + 2 * al(tpB);

  char* p = (char*)d_ws;
  ushort_t* mkh = (ushort_t*)p; p += al(mkB);
  ushort_t* mkl = (ushort_t*)p; p += al(mkB);
  ushort_t* qkh = (ushort_t*)p; p += al(qkB);
  ushort_t* qkl = (ushort_t*)p; p += al(qkB);
  float* ans    = (float*)p;    p += al(anB);
  float* pvals  = (float*)p;    p += al(prtB);
  int*   pidx   = (int*)p;      p += al(prtB);
  float* fw     = (float*)p;    p += al(finB);
  int*   fidx   = (int*)p;      p += al(finB);
  ushort_t* mvt0 = nullptr, * mvt1 = nullptr;
  if (tp) { mvt0 = (ushort_t*)p; p += al(tpB); mvt1 = (ushort_t*)p; p += al(tpB); }

  prep_mk<<<B_ * NM_ / 256, 256, 0, stream>>>(mk, mkh, mkl, ans);
  prep_qk<<<B_ * NQ_ / 256, 256, 0, stream>>>(qk, qkh, qkl);
  if (tp)
    transpose_mv<<<dim3(NM_ / 32, CV_ / 64, B_ * 2), 256, 0, stream>>>(mv0, mv1, mvt0, mvt1);
  score_topk_mfma<<<dim3(NQ_ / 256, SEG_, B_), 256, 0, stream>>>(mkh, mkl, qkh, qkl, ans, pvals, pidx);
  merge_kernel<<<B_ * NQ_ / 256, 256, 0, stream>>>(pvals, pidx, fw, fidx, SEG_);
  if (tp) readout_bf16<<<dim3(NQ_ / 16, B_), 256, 0, stream>>>(mvt0, mvt1, fw, fidx, out);
  else    readout_f32<<<dim3(NQ_ / 16, B_), 256, 0, stream>>>(mv0, mv1, fw, fidx, out);
}

// Round 3
// 789.835 us; speedup vs baseline: 10.8244x; 10.8244x over previous
//
#include <hip/hip_runtime.h>
#include <hip/hip_bf16.h>
#include <cstdint>

#define B_  2
#define CK_ 64
#define NM_ 32768
#define NQ_ 4096
#define CV_ 256
#define K_  20
#define SEG_ 16
#define LDSQ 34

typedef unsigned short ushort_t;
typedef unsigned int uint_t;
typedef unsigned long long u64_t;
typedef float f32x4 __attribute__((ext_vector_type(4)));
typedef float f32x2 __attribute__((ext_vector_type(2)));
typedef short short8v __attribute__((ext_vector_type(8)));

__device__ __forceinline__ ushort_t f2bf_rn(float f) {
  uint_t x = __float_as_uint(f);
  uint_t r = x + 0x7FFFu + ((x >> 16) & 1u);
  return (ushort_t)(r >> 16);
}
__device__ __forceinline__ float bf2f(ushort_t u) {
  return __uint_as_float(((uint_t)u) << 16);
}

// ------------------------------------------------------------------
__global__ __launch_bounds__(256) void prep_mk(const float* __restrict__ mk,
                                               ushort_t* __restrict__ mkh,
                                               ushort_t* __restrict__ mkl,
                                               float* __restrict__ ans) {
  int i = blockIdx.x * 256 + threadIdx.x;
  int b = i >> 15, m = i & (NM_ - 1);
  const float* src = mk + (size_t)b * CK_ * NM_ + m;
  ushort_t* dh = mkh + (size_t)i * CK_;
  ushort_t* dl = mkl + (size_t)i * CK_;
  float s = 0.f;
  #pragma unroll
  for (int c8 = 0; c8 < 8; ++c8) {
    ushort_t hh[8], ll[8];
    #pragma unroll
    for (int j = 0; j < 8; ++j) {
      float v = src[(size_t)(c8 * 8 + j) * NM_];
      s = fmaf(v, v, s);
      ushort_t h = f2bf_rn(v);
      hh[j] = h;
      ll[j] = f2bf_rn(v - bf2f(h));
    }
    *reinterpret_cast<short8v*>(dh + c8 * 8) = *reinterpret_cast<short8v*>(hh);
    *reinterpret_cast<short8v*>(dl + c8 * 8) = *reinterpret_cast<short8v*>(ll);
  }
  ans[i] = 0.125f * s;
}

__global__ __launch_bounds__(256) void prep_qk(const float* __restrict__ qk,
                                               ushort_t* __restrict__ qkh,
                                               ushort_t* __restrict__ qkl) {
  int i = blockIdx.x * 256 + threadIdx.x;
  int b = i >> 12, q = i & (NQ_ - 1);
  const float* src = qk + (size_t)b * CK_ * NQ_ + q;
  ushort_t* dh = qkh + (size_t)i * CK_;
  ushort_t* dl = qkl + (size_t)i * CK_;
  #pragma unroll
  for (int c8 = 0; c8 < 8; ++c8) {
    ushort_t hh[8], ll[8];
    #pragma unroll
    for (int j = 0; j < 8; ++j) {
      float v = 0.25f * src[(size_t)(c8 * 8 + j) * NQ_];
      ushort_t h = f2bf_rn(v);
      hh[j] = h;
      ll[j] = f2bf_rn(v - bf2f(h));
    }
    *reinterpret_cast<short8v*>(dh + c8 * 8) = *reinterpret_cast<short8v*>(hh);
    *reinterpret_cast<short8v*>(dl + c8 * 8) = *reinterpret_cast<short8v*>(ll);
  }
}

// ------------------------------------------------------------------
__global__ __launch_bounds__(256) void transpose_mv(const float* __restrict__ mv0,
                                                    const float* __restrict__ mv1,
                                                    ushort_t* __restrict__ mvt0,
                                                    ushort_t* __restrict__ mvt1) {
  __shared__ float tl[64][33];
  const int zz = blockIdx.z;
  const int bank = zz & 1, b = zz >> 1;
  const float* src = (bank ? mv1 : mv0) + (size_t)b * CV_ * NM_;
  ushort_t*    dst = (bank ? mvt1 : mvt0) + (size_t)b * NM_ * CV_;
  const int m0 = blockIdx.x * 32, c0 = blockIdx.y * 64;
  const int t = threadIdx.x;
  #pragma unroll
  for (int i = 0; i < 8; ++i) {
    int f = t + 256 * i;
    int c = f >> 5, ml = f & 31;
    tl[c][ml] = src[(size_t)(c0 + c) * NM_ + m0 + ml];
  }
  __syncthreads();
  int m = t >> 3, c8 = t & 7;
  ushort_t pack[8];
  #pragma unroll
  for (int j = 0; j < 8; ++j) pack[j] = f2bf_rn(tl[c8 * 8 + j][m]);
  *reinterpret_cast<short8v*>(dst + (size_t)(m0 + m) * CV_ + c0 + c8 * 8) =
      *reinterpret_cast<short8v*>(pack);
}

// ------------------------------------------------------------------
// top-k machinery: named scalars only, LDS candidate list, single INS instantiation per drain site
#define TK_FOR(F) F(0) F(1) F(2) F(3) F(4) F(5) F(6) F(7) F(8) F(9) F(10) F(11) F(12) F(13) F(14) F(15) F(16) F(17) F(18) F(19)

#define TK_DECL(J) float tv##J = -3.4e38f; int ti##J = 0;

#define TK_SW(A,B) { bool c_ = tv##A > tv##B; float t_ = tv##A; tv##A = c_ ? tv##B : t_; tv##B = c_ ? t_ : tv##B; int u_ = ti##A; ti##A = c_ ? ti##B : u_; ti##B = c_ ? u_ : ti##B; }

#define TK_INS(S,M) { if ((S) > tv19) { tv19 = (S); ti19 = (M); \
  TK_SW(19,18) TK_SW(18,17) TK_SW(17,16) TK_SW(16,15) TK_SW(15,14) \
  TK_SW(14,13) TK_SW(13,12) TK_SW(12,11) TK_SW(11,10) TK_SW(10,9) \
  TK_SW(9,8) TK_SW(8,7) TK_SW(7,6) TK_SW(6,5) TK_SW(5,4) \
  TK_SW(4,3) TK_SW(3,2) TK_SW(2,1) TK_SW(1,0) } }

#define TK_PUSH(S,M) { float s_ = (S); if (s_ > thr) { list_lds[(t << 3) + cnt] = (((u64_t)__float_as_uint(s_)) << 32) | (uint_t)(M); ++cnt; } }

#define TK_DRAIN() { \
  _Pragma("clang loop unroll(disable)") \
  for (int d_ = 0; d_ < 8; ++d_) { \
    if (d_ < cnt) { \
      u64_t pk_ = list_lds[(t << 3) + d_]; \
      float s_ = __uint_as_float((uint_t)(pk_ >> 32)); \
      int m_ = (int)(uint_t)(pk_ & 0xFFFFFFFFu); \
      TK_INS(s_, m_) \
    } } \
  cnt = 0; thr = tv19; }

#define TK_SCAN(CHP) { \
  const float* row_ = &S_lds[t * LDSQ]; \
  const int mb0_ = mseg0 + ((CHP) << 5); \
  _Pragma("clang loop unroll(disable)") \
  for (int jj_ = 0; jj_ < 8; ++jj_) { \
    f32x2 sa_ = *(const f32x2*)(row_ + 4 * jj_); \
    f32x2 sb_ = *(const f32x2*)(row_ + 4 * jj_ + 2); \
    int mb_ = mb0_ + 4 * jj_; \
    TK_PUSH(sa_[0], mb_) TK_PUSH(sa_[1], mb_ + 1) TK_PUSH(sb_[0], mb_ + 2) TK_PUSH(sb_[1], mb_ + 3) \
    if (__any(cnt >= 4)) TK_DRAIN() \
  } }

#define MFMA_BF16(A,B,C) __builtin_amdgcn_mfma_f32_16x16x32_bf16((A),(B),(C),0,0,0)

#define STORE_C(QT, MT, CREG) { \
  float* p_ = &S_lds[((w << 6) + ((QT) << 4) + lr) * LDSQ + ((MT) << 4) + (lg << 2)]; \
  f32x2 x_ = {CREG[0], CREG[1]}, y_ = {CREG[2], CREG[3]}; \
  *(f32x2*)p_ = x_; *(f32x2*)(p_ + 2) = y_; }

// block = 256 thr (4 waves): 256 queries x one m-segment. grid: (NQ/256, SEG_, B)
__global__ __launch_bounds__(256) void score_topk_mfma(
    const ushort_t* __restrict__ mkh, const ushort_t* __restrict__ mkl,
    const ushort_t* __restrict__ qkh, const ushort_t* __restrict__ qkl,
    const float* __restrict__ ans,
    float* __restrict__ pvals, int* __restrict__ pidx) {
  __shared__ float S_lds[256 * LDSQ];
  __shared__ u64_t list_lds[256 * 8];
  const int t = threadIdx.x;
  const int b = blockIdx.z, seg = blockIdx.y, qblk = blockIdx.x;
  const int mseg = NM_ / SEG_;
  const int chunks = mseg >> 5;
  const int w = t >> 6, l = t & 63;
  const int lr = l & 15, lg = l >> 4;
  const int mseg0 = seg * mseg;

  // B fragments (qk hi/lo), persistent in named registers
  short8v bh00, bh01, bh10, bh11, bh20, bh21, bh30, bh31;
  short8v bl00, bl01, bl10, bl11, bl20, bl21, bl30, bl31;
  {
    const size_t qrow = (size_t)b * NQ_ + qblk * 256 + w * 64 + lr;
    size_t base0 = (qrow << 6) + (lg << 3);
    bh00 = *(const short8v*)(qkh + base0);        bh01 = *(const short8v*)(qkh + base0 + 32);
    bl00 = *(const short8v*)(qkl + base0);        bl01 = *(const short8v*)(qkl + base0 + 32);
    size_t base1 = base0 + (16 << 6);
    bh10 = *(const short8v*)(qkh + base1);        bh11 = *(const short8v*)(qkh + base1 + 32);
    bl10 = *(const short8v*)(qkl + base1);        bl11 = *(const short8v*)(qkl + base1 + 32);
    size_t base2 = base0 + (32 << 6);
    bh20 = *(const short8v*)(qkh + base2);        bh21 = *(const short8v*)(qkh + base2 + 32);
    bl20 = *(const short8v*)(qkl + base2);        bl21 = *(const short8v*)(qkl + base2 + 32);
    size_t base3 = base0 + (48 << 6);
    bh30 = *(const short8v*)(qkh + base3);        bh31 = *(const short8v*)(qkh + base3 + 32);
    bl30 = *(const short8v*)(qkl + base3);        bl31 = *(const short8v*)(qkl + base3 + 32);
  }

  TK_FOR(TK_DECL)
  float thr = -3.4e38f;
  int cnt = 0;

  for (int ch = 0; ch < chunks; ++ch) {
    const int m0 = mseg0 + (ch << 5);
    const float* anp = ans + ((size_t)b << 15) + m0 + (lg << 2);
    f32x4 an0 = *(const f32x4*)anp;
    f32x4 an1 = *(const f32x4*)(anp + 16);
    f32x4 c00 = -an0, c01 = -an0, c02 = -an0, c03 = -an0;
    f32x4 c10 = -an1, c11 = -an1, c12 = -an1, c13 = -an1;
    {
      const size_t ar = (((size_t)b * NM_ + m0 + lr) << 6) + (lg << 3);
      short8v ah0 = *(const short8v*)(mkh + ar);
      short8v ah1 = *(const short8v*)(mkh + ar + 32);
      short8v al0 = *(const short8v*)(mkl + ar);
      short8v al1 = *(const short8v*)(mkl + ar + 32);
      c00 = MFMA_BF16(ah0, bh00, c00); c01 = MFMA_BF16(ah0, bh10, c01);
      c02 = MFMA_BF16(ah0, bh20, c02); c03 = MFMA_BF16(ah0, bh30, c03);
      c00 = MFMA_BF16(ah1, bh01, c00); c01 = MFMA_BF16(ah1, bh11, c01);
      c02 = MFMA_BF16(ah1, bh21, c02); c03 = MFMA_BF16(ah1, bh31, c03);
      c00 = MFMA_BF16(ah0, bl00, c00); c01 = MFMA_BF16(ah0, bl10, c01);
      c02 = MFMA_BF16(ah0, bl20, c02); c03 = MFMA_BF16(ah0, bl30, c03);
      c00 = MFMA_BF16(ah1, bl01, c00); c01 = MFMA_BF16(ah1, bl11, c01);
      c02 = MFMA_BF16(ah1, bl21, c02); c03 = MFMA_BF16(ah1, bl31, c03);
      c00 = MFMA_BF16(al0, bh00, c00); c01 = MFMA_BF16(al0, bh10, c01);
      c02 = MFMA_BF16(al0, bh20, c02); c03 = MFMA_BF16(al0, bh30, c03);
      c00 = MFMA_BF16(al1, bh01, c00); c01 = MFMA_BF16(al1, bh11, c01);
      c02 = MFMA_BF16(al1, bh21, c02); c03 = MFMA_BF16(al1, bh31, c03);
    }
    {
      const size_t ar = (((size_t)b * NM_ + m0 + 16 + lr) << 6) + (lg << 3);
      short8v ah0 = *(const short8v*)(mkh + ar);
      short8v ah1 = *(const short8v*)(mkh + ar + 32);
      short8v al0 = *(const short8v*)(mkl + ar);
      short8v al1 = *(const short8v*)(mkl + ar + 32);
      c10 = MFMA_BF16(ah0, bh00, c10); c11 = MFMA_BF16(ah0, bh10, c11);
      c12 = MFMA_BF16(ah0, bh20, c12); c13 = MFMA_BF16(ah0, bh30, c13);
      c10 = MFMA_BF16(ah1, bh01, c10); c11 = MFMA_BF16(ah1, bh11, c11);
      c12 = MFMA_BF16(ah1, bh21, c12); c13 = MFMA_BF16(ah1, bh31, c13);
      c10 = MFMA_BF16(ah0, bl00, c10); c11 = MFMA_BF16(ah0, bl10, c11);
      c12 = MFMA_BF16(ah0, bl20, c12); c13 = MFMA_BF16(ah0, bl30, c13);
      c10 = MFMA_BF16(ah1, bl01, c10); c11 = MFMA_BF16(ah1, bl11, c11);
      c12 = MFMA_BF16(ah1, bl21, c12); c13 = MFMA_BF16(ah1, bl31, c13);
      c10 = MFMA_BF16(al0, bh00, c10); c11 = MFMA_BF16(al0, bh10, c11);
      c12 = MFMA_BF16(al0, bh20, c12); c13 = MFMA_BF16(al0, bh30, c13);
      c10 = MFMA_BF16(al1, bh01, c10); c11 = MFMA_BF16(al1, bh11, c11);
      c12 = MFMA_BF16(al1, bh21, c12); c13 = MFMA_BF16(al1, bh31, c13);
    }

    // scan previous chunk's scores while MFMAs drain
    if (ch > 0) { TK_SCAN(ch - 1) }
    __syncthreads();

    STORE_C(0, 0, c00) STORE_C(1, 0, c01) STORE_C(2, 0, c02) STORE_C(3, 0, c03)
    STORE_C(0, 1, c10) STORE_C(1, 1, c11) STORE_C(2, 1, c12) STORE_C(3, 1, c13)
    __syncthreads();
  }
  TK_SCAN(chunks - 1)
  if (__any(cnt >= 1)) TK_DRAIN()

  const int q = (qblk << 8) + t;
  float* pv = pvals + (((size_t)(b * SEG_ + seg) * K_) << 12) + q;
  int*   pi = pidx  + (((size_t)(b * SEG_ + seg) * K_) << 12) + q;
#define TK_STORE(J) { pv[(size_t)(J) << 12] = tv##J; pi[(size_t)(J) << 12] = ti##J; }
  TK_FOR(TK_STORE)
#undef TK_STORE
}

// ------------------------------------------------------------------
__global__ __launch_bounds__(256) void merge_kernel(const float* __restrict__ pvals,
                                                    const int* __restrict__ pidx,
                                                    float* __restrict__ fw,
                                                    int* __restrict__ fidx, int S) {
  int i = blockIdx.x * 256 + threadIdx.x;
  int b = i >> 12, q = i & (NQ_ - 1);

  float vals[K_]; int idxs[K_];
  #pragma unroll
  for (int j = 0; j < K_; ++j) { vals[j] = -3.4e38f; idxs[j] = 0; }

  for (int seg = 0; seg < S; ++seg) {
    #pragma unroll
    for (int j = 0; j < K_; ++j) {
      size_t o = (size_t)((b * S + seg) * K_ + j) * NQ_ + q;
      float v = pvals[o];
      if (v > vals[K_ - 1]) {
        int m = pidx[o];
        vals[K_ - 1] = v; idxs[K_ - 1] = m;
        #pragma unroll
        for (int jj = K_ - 1; jj > 0; --jj) {
          if (vals[jj] > vals[jj - 1]) {
            float tv = vals[jj]; vals[jj] = vals[jj - 1]; vals[jj - 1] = tv;
            int   ti = idxs[jj]; idxs[jj] = idxs[jj - 1]; idxs[jj - 1] = ti;
          }
        }
      }
    }
  }

  float mx = vals[0];
  float w[K_]; float sum = 0.f;
  #pragma unroll
  for (int j = 0; j < K_; ++j) { w[j] = expf(vals[j] - mx); sum += w[j]; }
  float inv = 1.f / sum;
  #pragma unroll
  for (int j = 0; j < K_; ++j) {
    size_t o = (size_t)(b * K_ + j) * NQ_ + q;
    fw[o] = w[j] * inv; fidx[o] = idxs[j];
  }
}

// ------------------------------------------------------------------
__global__ __launch_bounds__(256) void readout_bf16(const ushort_t* __restrict__ mvt0,
                                                    const ushort_t* __restrict__ mvt1,
                                                    const float* __restrict__ fw,
                                                    const int* __restrict__ fidx,
                                                    float* __restrict__ out) {
  __shared__ float mw[16][K_];
  __shared__ int   mi[16][K_];
  __shared__ float ob0[256][17];
  __shared__ float ob1[256][17];
  const int t = threadIdx.x;
  const int b = blockIdx.y;
  const int q0 = blockIdx.x * 16;

  for (int i = t; i < 16 * K_; i += 256) {
    int qp = i / K_, k = i % K_;
    size_t o = (size_t)(b * K_ + k) * NQ_ + q0 + qp;
    mw[qp][k] = fw[o];
    mi[qp][k] = fidx[o];
  }
  __syncthreads();

  const int c2 = (t & 127) * 2, hq = t >> 7;
  for (int qp = hq * 8; qp < hq * 8 + 8; ++qp) {
    float a00 = 0.f, a01 = 0.f, a10 = 0.f, a11 = 0.f;
    #pragma unroll 5
    for (int k = 0; k < K_; ++k) {
      int m = mi[qp][k]; float ww = mw[qp][k];
      size_t o = ((size_t)(b * NM_ + m) << 8) + c2;
      uint_t v0 = *reinterpret_cast<const uint_t*>(mvt0 + o);
      uint_t v1 = *reinterpret_cast<const uint_t*>(mvt1 + o);
      a00 = fmaf(ww, __uint_as_float(v0 << 16), a00);
      a01 = fmaf(ww, __uint_as_float(v0 & 0xFFFF0000u), a01);
      a10 = fmaf(ww, __uint_as_float(v1 << 16), a10);
      a11 = fmaf(ww, __uint_as_float(v1 & 0xFFFF0000u), a11);
    }
    ob0[c2][qp] = a00; ob0[c2 + 1][qp] = a01;
    ob1[c2][qp] = a10; ob1[c2 + 1][qp] = a11;
  }
  __syncthreads();

  float* out0 = out + (size_t)b * CV_ * NQ_;
  float* out1 = out + (size_t)B_ * CV_ * NQ_ + (size_t)b * CV_ * NQ_;
  for (int i = t; i < 256 * 16; i += 256) {
    int c = i >> 4, qp = i & 15;
    out0[(size_t)c * NQ_ + q0 + qp] = ob0[c][qp];
    out1[(size_t)c * NQ_ + q0 + qp] = ob1[c][qp];
  }
}

__global__ __launch_bounds__(256) void readout_f32(const float* __restrict__ v0src,
                                                   const float* __restrict__ v1src,
                                                   const float* __restrict__ fw,
                                                   const int* __restrict__ fidx,
                                                   float* __restrict__ out) {
  __shared__ float mw[16][K_];
  __shared__ int   mi[16][K_];
  __shared__ float ob0[256][17];
  __shared__ float ob1[256][17];
  const int t = threadIdx.x;
  const int b = blockIdx.y;
  const int q0 = blockIdx.x * 16;

  for (int i = t; i < 16 * K_; i += 256) {
    int qp = i / K_, k = i % K_;
    size_t o = (size_t)(b * K_ + k) * NQ_ + q0 + qp;
    mw[qp][k] = fw[o];
    mi[qp][k] = fidx[o];
  }
  __syncthreads();

  for (int qp = 0; qp < 16; ++qp) {
    float a0 = 0.f, a1 = 0.f;
    #pragma unroll 5
    for (int k = 0; k < K_; ++k) {
      int m = mi[qp][k]; float ww = mw[qp][k];
      size_t o = (size_t)b * CV_ * NM_ + (size_t)t * NM_ + m;
      a0 = fmaf(ww, v0src[o], a0);
      a1 = fmaf(ww, v1src[o], a1);
    }
    ob0[t][qp] = a0; ob1[t][qp] = a1;
  }
  __syncthreads();

  float* out0 = out + (size_t)b * CV_ * NQ_;
  float* out1 = out + (size_t)B_ * CV_ * NQ_ + (size_t)b * CV_ * NQ_;
  for (int i = t; i < 256 * 16; i += 256) {
    int c = i >> 4, qp = i & 15;
    out0[(size_t)c * NQ_ + q0 + qp] = ob0[c][qp];
    out1[(size_t)c * NQ_ + q0 + qp] = ob1[c][qp];
  }
}

// ------------------------------------------------------------------
extern "C" void kernel_launch(void* const* d_in, const int* in_sizes, int n_in,
                              void* d_out, int out_size, void* d_ws, size_t ws_size,
                              hipStream_t stream) {
  (void)in_sizes; (void)n_in; (void)out_size;
  const float* mk  = (const float*)d_in[0];
  const float* qk  = (const float*)d_in[1];
  const float* mv0 = (const float*)d_in[2];
  const float* mv1 = (const float*)d_in[3];
  float* out = (float*)d_out;

  auto al = [](size_t x) { return (x + 255) & ~(size_t)255; };
  const size_t mkB  = (size_t)B_ * NM_ * CK_ * 2;
  const size_t qkB  = (size_t)B_ * NQ_ * CK_ * 2;
  const size_t anB  = (size_t)B_ * NM_ * 4;
  const size_t prtB = (size_t)B_ * SEG_ * K_ * NQ_ * 4;
  const size_t finB = (size_t)B_ * K_ * NQ_ * 4;
  const size_t tpB  = (size_t)B_ * NM_ * CV_ * 2;

  const size_t core = 2 * al(mkB) + 2 * al(qkB) + al(anB) + 2 * al(prtB) + 2 * al(finB);
  const bool tp = ws_size >= core + 2 * al(tpB);

  char* p = (char*)d_ws;
  ushort_t* mkh = (ushort_t*)p; p += al(mkB);
  ushort_t* mkl = (ushort_t*)p; p += al(mkB);
  ushort_t* qkh = (ushort_t*)p; p += al(qkB);
  ushort_t* qkl = (ushort_t*)p; p += al(qkB);
  float* ans    = (float*)p;    p += al(anB);
  float* pvals  = (float*)p;    p += al(prtB);
  int*   pidx   = (int*)p;      p += al(prtB);
  float* fw     = (float*)p;    p += al(finB);
  int*   fidx   = (int*)p;      p += al(finB);
  ushort_t* mvt0 = nullptr, * mvt1 = nullptr;
  if (tp) { mvt0 = (ushort_t*)p; p += al(tpB); mvt1 = (ushort_t*)p; p += al(tpB); }

  prep_mk<<<B_ * NM_ / 256, 256, 0, stream>>>(mk, mkh, mkl, ans);
  prep_qk<<<B_ * NQ_ / 256, 256, 0, stream>>>(qk, qkh, qkl);
  if (tp)
    transpose_mv<<<dim3(NM_ / 32, CV_ / 64, B_ * 2), 256, 0, stream>>>(mv0, mv1, mvt0, mvt1);
  score_topk_mfma<<<dim3(NQ_ / 256, SEG_, B_), 256, 0, stream>>>(mkh, mkl, qkh, qkl, ans, pvals, pidx);
  merge_kernel<<<B_ * NQ_ / 256, 256, 0, stream>>>(pvals, pidx, fw, fidx, SEG_);
  if (tp) readout_bf16<<<dim3(NQ_ / 16, B_), 256, 0, stream>>>(mvt0, mvt1, fw, fidx, out);
  else    readout_f32<<<dim3(NQ_ / 16, B_), 256, 0, stream>>>(mv0, mv1, fw, fidx, out);
}

// Round 5
// 629.295 us; speedup vs baseline: 13.5858x; 1.2551x over previous
//
#include <hip/hip_runtime.h>
#include <hip/hip_bf16.h>
#include <cstdint>

#define B_  2
#define CK_ 64
#define NM_ 32768
#define NQ_ 4096
#define CV_ 256
#define K_  20
#define SEG2_ 8      // m-segments; each thread-pair half-covers -> 16 partitions
#define PARTS_ 16

typedef unsigned short ushort_t;
typedef unsigned int uint_t;
typedef unsigned long long u64_t;
typedef float f32x4 __attribute__((ext_vector_type(4)));
typedef float f32x16 __attribute__((ext_vector_type(16)));
typedef short short8v __attribute__((ext_vector_type(8)));

__device__ __forceinline__ ushort_t f2bf_rn(float f) {
  uint_t x = __float_as_uint(f);
  uint_t r = x + 0x7FFFu + ((x >> 16) & 1u);
  return (ushort_t)(r >> 16);
}
__device__ __forceinline__ float bf2f(ushort_t u) {
  return __uint_as_float(((uint_t)u) << 16);
}

// ------------------------------------------------------------------
__global__ __launch_bounds__(256) void prep_mk(const float* __restrict__ mk,
                                               ushort_t* __restrict__ mkh,
                                               ushort_t* __restrict__ mkl,
                                               float* __restrict__ ans) {
  int i = blockIdx.x * 256 + threadIdx.x;
  int b = i >> 15, m = i & (NM_ - 1);
  const float* src = mk + (size_t)b * CK_ * NM_ + m;
  ushort_t* dh = mkh + (size_t)i * CK_;
  ushort_t* dl = mkl + (size_t)i * CK_;
  float s = 0.f;
  #pragma unroll
  for (int c8 = 0; c8 < 8; ++c8) {
    ushort_t hh[8], ll[8];
    #pragma unroll
    for (int j = 0; j < 8; ++j) {
      float v = src[(size_t)(c8 * 8 + j) * NM_];
      s = fmaf(v, v, s);
      ushort_t h = f2bf_rn(v);
      hh[j] = h;
      ll[j] = f2bf_rn(v - bf2f(h));
    }
    *reinterpret_cast<short8v*>(dh + c8 * 8) = *reinterpret_cast<short8v*>(hh);
    *reinterpret_cast<short8v*>(dl + c8 * 8) = *reinterpret_cast<short8v*>(ll);
  }
  ans[i] = 0.125f * s;
}

__global__ __launch_bounds__(256) void prep_qk(const float* __restrict__ qk,
                                               ushort_t* __restrict__ qkh,
                                               ushort_t* __restrict__ qkl) {
  int i = blockIdx.x * 256 + threadIdx.x;
  int b = i >> 12, q = i & (NQ_ - 1);
  const float* src = qk + (size_t)b * CK_ * NQ_ + q;
  ushort_t* dh = qkh + (size_t)i * CK_;
  ushort_t* dl = qkl + (size_t)i * CK_;
  #pragma unroll
  for (int c8 = 0; c8 < 8; ++c8) {
    ushort_t hh[8], ll[8];
    #pragma unroll
    for (int j = 0; j < 8; ++j) {
      float v = 0.25f * src[(size_t)(c8 * 8 + j) * NQ_];
      ushort_t h = f2bf_rn(v);
      hh[j] = h;
      ll[j] = f2bf_rn(v - bf2f(h));
    }
    *reinterpret_cast<short8v*>(dh + c8 * 8) = *reinterpret_cast<short8v*>(hh);
    *reinterpret_cast<short8v*>(dl + c8 * 8) = *reinterpret_cast<short8v*>(ll);
  }
}

// ------------------------------------------------------------------
__global__ __launch_bounds__(256) void transpose_mv(const float* __restrict__ mv0,
                                                    const float* __restrict__ mv1,
                                                    ushort_t* __restrict__ mvt0,
                                                    ushort_t* __restrict__ mvt1) {
  __shared__ float tl[64][33];
  const int zz = blockIdx.z;
  const int bank = zz & 1, b = zz >> 1;
  const float* src = (bank ? mv1 : mv0) + (size_t)b * CV_ * NM_;
  ushort_t*    dst = (bank ? mvt1 : mvt0) + (size_t)b * NM_ * CV_;
  const int m0 = blockIdx.x * 32, c0 = blockIdx.y * 64;
  const int t = threadIdx.x;
  #pragma unroll
  for (int i = 0; i < 8; ++i) {
    int f = t + 256 * i;
    int c = f >> 5, ml = f & 31;
    tl[c][ml] = src[(size_t)(c0 + c) * NM_ + m0 + ml];
  }
  __syncthreads();
  int m = t >> 3, c8 = t & 7;
  ushort_t pack[8];
  #pragma unroll
  for (int j = 0; j < 8; ++j) pack[j] = f2bf_rn(tl[c8 * 8 + j][m]);
  *reinterpret_cast<short8v*>(dst + (size_t)(m0 + m) * CV_ + c0 + c8 * 8) =
      *reinterpret_cast<short8v*>(pack);
}

// ------------------------------------------------------------------
// exact fp32 top-20: named scalar pairs, fmax/fmin + cndmask ripple
#define TKF_FOR(F) F(0) F(1) F(2) F(3) F(4) F(5) F(6) F(7) F(8) F(9) F(10) F(11) F(12) F(13) F(14) F(15) F(16) F(17) F(18) F(19)
#define TKF_DECL(J) float tv##J = -3.4e38f; int ti##J = 0;

#define TKF_SW(A,B) { bool c_ = tv##B > tv##A; \
  float fx_ = fmaxf(tv##A, tv##B); float fn_ = fminf(tv##A, tv##B); \
  int ix_ = c_ ? ti##B : ti##A;    int in_ = c_ ? ti##A : ti##B; \
  tv##A = fx_; tv##B = fn_; ti##A = ix_; ti##B = in_; }

#define TKF_INS(S,M) { if ((S) > tv19) { tv19 = (S); ti19 = (M); \
  TKF_SW(18,19) TKF_SW(17,18) TKF_SW(16,17) TKF_SW(15,16) TKF_SW(14,15) \
  TKF_SW(13,14) TKF_SW(12,13) TKF_SW(11,12) TKF_SW(10,11) TKF_SW(9,10) \
  TKF_SW(8,9) TKF_SW(7,8) TKF_SW(6,7) TKF_SW(5,6) TKF_SW(4,5) \
  TKF_SW(3,4) TKF_SW(2,3) TKF_SW(1,2) TKF_SW(0,1) } }

#define TKF_PUSH(S,M) { float s_ = (S); if (s_ > tv19) { \
  caf5 = caf4; cam5 = cam4; caf4 = caf3; cam4 = cam3; caf3 = caf2; cam3 = cam2; \
  caf2 = caf1; cam2 = cam1; caf1 = caf0; cam1 = cam0; caf0 = s_; cam0 = (M); ++cnt; } }

#define TKD_ONE(J) { float sd_ = (cnt > (J)) ? caf##J : -3.4e38f; int md_ = cam##J; TKF_INS(sd_, md_) }
#define TKF_DRAIN() { TKD_ONE(0) TKD_ONE(1) TKD_ONE(2) TKD_ONE(3) TKD_ONE(4) TKD_ONE(5) cnt = 0; }
#define TKF_CHK() { if (__any(cnt >= 3)) { TKF_DRAIN() } }

#define MFMA32(A,B,C) __builtin_amdgcn_mfma_f32_32x32x16_bf16((A),(B),(C),0,0,0)

// score + exact top-20, no LDS. block = 256 thr (4 waves) = 128 queries (2 thr/query).
// grid: (NQ/128, SEG2_, B). Each thread covers half the segment's m (interleaved 4-blocks).
__global__ __launch_bounds__(256) void score_topk_mfma(
    const ushort_t* __restrict__ mkh, const ushort_t* __restrict__ mkl,
    const ushort_t* __restrict__ qkh, const ushort_t* __restrict__ qkl,
    const float* __restrict__ ans,
    float* __restrict__ pvals, int* __restrict__ pidx) {
  const int t = threadIdx.x;
  const int b = blockIdx.z, seg = blockIdx.y, qblk = blockIdx.x;
  const int w = t >> 6, l = t & 63;
  const int lq = l & 31, hi = l >> 5;
  const int q = qblk * 128 + w * 32 + lq;
  const int mseg = NM_ / SEG2_;          // 4096
  const int chunks = mseg >> 5;          // 128
  const int mseg0 = seg * mseg;

  // persistent B (qk hi) fragments: B[k][q], col=lane&31=q, k = kstep*16 + hi*8 + j
  const size_t qbase = (((size_t)b * NQ_ + q) << 6) + hi * 8;
  const short8v bh0 = *(const short8v*)(qkh + qbase);
  const short8v bh1 = *(const short8v*)(qkh + qbase + 16);
  const short8v bh2 = *(const short8v*)(qkh + qbase + 32);
  const short8v bh3 = *(const short8v*)(qkh + qbase + 48);

  TKF_FOR(TKF_DECL)
  float caf0 = 0, caf1 = 0, caf2 = 0, caf3 = 0, caf4 = 0, caf5 = 0;
  int cam0 = 0, cam1 = 0, cam2 = 0, cam3 = 0, cam4 = 0, cam5 = 0;
  int cnt = 0;

  #pragma clang loop unroll(disable)
  for (int ch = 0; ch < chunks; ++ch) {
    const int m0 = mseg0 + (ch << 5);

    // A (mk) fragments: row = lane&31 = m-local, k = kstep*16 + hi*8 + j
    const size_t abase = (((size_t)b * NM_ + m0 + lq) << 6) + hi * 8;
    short8v ah0 = *(const short8v*)(mkh + abase);
    short8v ah1 = *(const short8v*)(mkh + abase + 16);
    short8v ah2 = *(const short8v*)(mkh + abase + 32);
    short8v ah3 = *(const short8v*)(mkh + abase + 48);
    short8v al0 = *(const short8v*)(mkl + abase);
    short8v al1 = *(const short8v*)(mkl + abase + 16);
    short8v al2 = *(const short8v*)(mkl + abase + 32);
    short8v al3 = *(const short8v*)(mkl + abase + 48);
    short8v bl0 = *(const short8v*)(qkl + qbase);
    short8v bl1 = *(const short8v*)(qkl + qbase + 16);
    short8v bl2 = *(const short8v*)(qkl + qbase + 32);
    short8v bl3 = *(const short8v*)(qkl + qbase + 48);

    // acc init = -0.125*||mk||^2 ; D rows: (reg&3) + 8*(reg>>2) + 4*hi
    const float* anp = ans + ((size_t)b << 15) + m0 + 4 * hi;
    f32x4 an_a = *(const f32x4*)anp;
    f32x4 an_b = *(const f32x4*)(anp + 8);
    f32x4 an_c = *(const f32x4*)(anp + 16);
    f32x4 an_d = *(const f32x4*)(anp + 24);
    f32x16 acc;
    acc[0]  = -an_a[0]; acc[1]  = -an_a[1]; acc[2]  = -an_a[2]; acc[3]  = -an_a[3];
    acc[4]  = -an_b[0]; acc[5]  = -an_b[1]; acc[6]  = -an_b[2]; acc[7]  = -an_b[3];
    acc[8]  = -an_c[0]; acc[9]  = -an_c[1]; acc[10] = -an_c[2]; acc[11] = -an_c[3];
    acc[12] = -an_d[0]; acc[13] = -an_d[1]; acc[14] = -an_d[2]; acc[15] = -an_d[3];

    acc = MFMA32(ah0, bh0, acc);
    acc = MFMA32(ah1, bh1, acc);
    acc = MFMA32(ah2, bh2, acc);
    acc = MFMA32(ah3, bh3, acc);
    acc = MFMA32(ah0, bl0, acc);
    acc = MFMA32(ah1, bl1, acc);
    acc = MFMA32(ah2, bl2, acc);
    acc = MFMA32(ah3, bl3, acc);
    acc = MFMA32(al0, bh0, acc);
    acc = MFMA32(al1, bh1, acc);
    acc = MFMA32(al2, bh2, acc);
    acc = MFMA32(al3, bh3, acc);

    // scan own accumulator registers; exact fp32 selection
    const int mb = m0 + 4 * hi;
#define PUSH_E(R, OFF) TKF_PUSH(acc[R], mb + (OFF))
    PUSH_E(0, 0)  PUSH_E(1, 1)  PUSH_E(2, 2)  PUSH_E(3, 3)  TKF_CHK()
    PUSH_E(4, 8)  PUSH_E(5, 9)  PUSH_E(6, 10) PUSH_E(7, 11) TKF_CHK()
    PUSH_E(8, 16) PUSH_E(9, 17) PUSH_E(10,18) PUSH_E(11,19) TKF_CHK()
    PUSH_E(12,24) PUSH_E(13,25) PUSH_E(14,26) PUSH_E(15,27) TKF_CHK()
#undef PUSH_E
  }
  if (__any(cnt > 0)) { TKF_DRAIN() }

  const int part = (seg << 1) + hi;
  float* pv = pvals + (((size_t)((b * PARTS_ + part) * K_)) << 12) + q;
  int*   pi = pidx  + (((size_t)((b * PARTS_ + part) * K_)) << 12) + q;
#define TKF_STORE(J) { pv[(size_t)(J) << 12] = tv##J; pi[(size_t)(J) << 12] = ti##J; }
  TKF_FOR(TKF_STORE)
#undef TKF_STORE
}

// ------------------------------------------------------------------
__global__ __launch_bounds__(256) void merge_kernel(const float* __restrict__ pvals,
                                                    const int* __restrict__ pidx,
                                                    float* __restrict__ fw,
                                                    int* __restrict__ fidx, int S) {
  int i = blockIdx.x * 256 + threadIdx.x;
  int b = i >> 12, q = i & (NQ_ - 1);

  float vals[K_]; int idxs[K_];
  #pragma unroll
  for (int j = 0; j < K_; ++j) { vals[j] = -3.4e38f; idxs[j] = 0; }

  for (int seg = 0; seg < S; ++seg) {
    #pragma unroll
    for (int j = 0; j < K_; ++j) {
      size_t o = (size_t)((b * S + seg) * K_ + j) * NQ_ + q;
      float v = pvals[o];
      if (v > vals[K_ - 1]) {
        int m = pidx[o];
        vals[K_ - 1] = v; idxs[K_ - 1] = m;
        #pragma unroll
        for (int jj = K_ - 1; jj > 0; --jj) {
          if (vals[jj] > vals[jj - 1]) {
            float tv = vals[jj]; vals[jj] = vals[jj - 1]; vals[jj - 1] = tv;
            int   ti = idxs[jj]; idxs[jj] = idxs[jj - 1]; idxs[jj - 1] = ti;
          }
        }
      }
    }
  }

  float mx = vals[0];
  float w[K_]; float sum = 0.f;
  #pragma unroll
  for (int j = 0; j < K_; ++j) { w[j] = expf(vals[j] - mx); sum += w[j]; }
  float inv = 1.f / sum;
  #pragma unroll
  for (int j = 0; j < K_; ++j) {
    size_t o = (size_t)(b * K_ + j) * NQ_ + q;
    fw[o] = w[j] * inv; fidx[o] = idxs[j];
  }
}

// ------------------------------------------------------------------
__global__ __launch_bounds__(256) void readout_bf16(const ushort_t* __restrict__ mvt0,
                                                    const ushort_t* __restrict__ mvt1,
                                                    const float* __restrict__ fw,
                                                    const int* __restrict__ fidx,
                                                    float* __restrict__ out) {
  __shared__ float mw[16][K_];
  __shared__ int   mi[16][K_];
  __shared__ float ob0[256][17];
  __shared__ float ob1[256][17];
  const int t = threadIdx.x;
  const int b = blockIdx.y;
  const int q0 = blockIdx.x * 16;

  for (int i = t; i < 16 * K_; i += 256) {
    int qp = i / K_, k = i % K_;
    size_t o = (size_t)(b * K_ + k) * NQ_ + q0 + qp;
    mw[qp][k] = fw[o];
    mi[qp][k] = fidx[o];
  }
  __syncthreads();

  const int c2 = (t & 127) * 2, hq = t >> 7;
  for (int qp = hq * 8; qp < hq * 8 + 8; ++qp) {
    float a00 = 0.f, a01 = 0.f, a10 = 0.f, a11 = 0.f;
    #pragma unroll 5
    for (int k = 0; k < K_; ++k) {
      int m = mi[qp][k]; float ww = mw[qp][k];
      size_t o = ((size_t)(b * NM_ + m) << 8) + c2;
      uint_t v0 = *reinterpret_cast<const uint_t*>(mvt0 + o);
      uint_t v1 = *reinterpret_cast<const uint_t*>(mvt1 + o);
      a00 = fmaf(ww, __uint_as_float(v0 << 16), a00);
      a01 = fmaf(ww, __uint_as_float(v0 & 0xFFFF0000u), a01);
      a10 = fmaf(ww, __uint_as_float(v1 << 16), a10);
      a11 = fmaf(ww, __uint_as_float(v1 & 0xFFFF0000u), a11);
    }
    ob0[c2][qp] = a00; ob0[c2 + 1][qp] = a01;
    ob1[c2][qp] = a10; ob1[c2 + 1][qp] = a11;
  }
  __syncthreads();

  float* out0 = out + (size_t)b * CV_ * NQ_;
  float* out1 = out + (size_t)B_ * CV_ * NQ_ + (size_t)b * CV_ * NQ_;
  for (int i = t; i < 256 * 16; i += 256) {
    int c = i >> 4, qp = i & 15;
    out0[(size_t)c * NQ_ + q0 + qp] = ob0[c][qp];
    out1[(size_t)c * NQ_ + q0 + qp] = ob1[c][qp];
  }
}

__global__ __launch_bounds__(256) void readout_f32(const float* __restrict__ v0src,
                                                   const float* __restrict__ v1src,
                                                   const float* __restrict__ fw,
                                                   const int* __restrict__ fidx,
                                                   float* __restrict__ out) {
  __shared__ float mw[16][K_];
  __shared__ int   mi[16][K_];
  __shared__ float ob0[256][17];
  __shared__ float ob1[256][17];
  const int t = threadIdx.x;
  const int b = blockIdx.y;
  const int q0 = blockIdx.x * 16;

  for (int i = t; i < 16 * K_; i += 256) {
    int qp = i / K_, k = i % K_;
    size_t o = (size_t)(b * K_ + k) * NQ_ + q0 + qp;
    mw[qp][k] = fw[o];
    mi[qp][k] = fidx[o];
  }
  __syncthreads();

  for (int qp = 0; qp < 16; ++qp) {
    float a0 = 0.f, a1 = 0.f;
    #pragma unroll 5
    for (int k = 0; k < K_; ++k) {
      int m = mi[qp][k]; float ww = mw[qp][k];
      size_t o = (size_t)b * CV_ * NM_ + (size_t)t * NM_ + m;
      a0 = fmaf(ww, v0src[o], a0);
      a1 = fmaf(ww, v1src[o], a1);
    }
    ob0[t][qp] = a0; ob1[t][qp] = a1;
  }
  __syncthreads();

  float* out0 = out + (size_t)b * CV_ * NQ_;
  float* out1 = out + (size_t)B_ * CV_ * NQ_ + (size_t)b * CV_ * NQ_;
  for (int i = t; i < 256 * 16; i += 256) {
    int c = i >> 4, qp = i & 15;
    out0[(size_t)c * NQ_ + q0 + qp] = ob0[c][qp];
    out1[(size_t)c * NQ_ + q0 + qp] = ob1[c][qp];
  }
}

// ------------------------------------------------------------------
extern "C" void kernel_launch(void* const* d_in, const int* in_sizes, int n_in,
                              void* d_out, int out_size, void* d_ws, size_t ws_size,
                              hipStream_t stream) {
  (void)in_sizes; (void)n_in; (void)out_size;
  const float* mk  = (const float*)d_in[0];
  const float* qk  = (const float*)d_in[1];
  const float* mv0 = (const float*)d_in[2];
  const float* mv1 = (const float*)d_in[3];
  float* out = (float*)d_out;

  auto al = [](size_t x) { return (x + 255) & ~(size_t)255; };
  const size_t mkB  = (size_t)B_ * NM_ * CK_ * 2;
  const size_t qkB  = (size_t)B_ * NQ_ * CK_ * 2;
  const size_t anB  = (size_t)B_ * NM_ * 4;
  const size_t prtB = (size_t)B_ * PARTS_ * K_ * NQ_ * 4;
  const size_t finB = (size_t)B_ * K_ * NQ_ * 4;
  const size_t tpB  = (size_t)B_ * NM_ * CV_ * 2;

  const size_t core = 2 * al(mkB) + 2 * al(qkB) + al(anB) + 2 * al(prtB) + 2 * al(finB);
  const bool tp = ws_size >= core + 2 * al(tpB);

  char* p = (char*)d_ws;
  ushort_t* mkh = (ushort_t*)p; p += al(mkB);
  ushort_t* mkl = (ushort_t*)p; p += al(mkB);
  ushort_t* qkh = (ushort_t*)p; p += al(qkB);
  ushort_t* qkl = (ushort_t*)p; p += al(qkB);
  float* ans    = (float*)p;    p += al(anB);
  float* pvals  = (float*)p;    p += al(prtB);
  int*   pidx   = (int*)p;      p += al(prtB);
  float* fw     = (float*)p;    p += al(finB);
  int*   fidx   = (int*)p;      p += al(finB);
  ushort_t* mvt0 = nullptr, * mvt1 = nullptr;
  if (tp) { mvt0 = (ushort_t*)p; p += al(tpB); mvt1 = (ushort_t*)p; p += al(tpB); }

  prep_mk<<<B_ * NM_ / 256, 256, 0, stream>>>(mk, mkh, mkl, ans);
  prep_qk<<<B_ * NQ_ / 256, 256, 0, stream>>>(qk, qkh, qkl);
  if (tp)
    transpose_mv<<<dim3(NM_ / 32, CV_ / 64, B_ * 2), 256, 0, stream>>>(mv0, mv1, mvt0, mvt1);
  score_topk_mfma<<<dim3(NQ_ / 128, SEG2_, B_), 256, 0, stream>>>(mkh, mkl, qkh, qkl, ans, pvals, pidx);
  merge_kernel<<<B_ * NQ_ / 256, 256, 0, stream>>>(pvals, pidx, fw, fidx, PARTS_);
  if (tp) readout_bf16<<<dim3(NQ_ / 16, B_), 256, 0, stream>>>(mvt0, mvt1, fw, fidx, out);
  else    readout_f32<<<dim3(NQ_ / 16, B_), 256, 0, stream>>>(mv0, mv1, fw, fidx, out);
}

// Round 6
// 600.071 us; speedup vs baseline: 14.2475x; 1.0487x over previous
//
#include <hip/hip_runtime.h>
#include <hip/hip_bf16.h>
#include <cstdint>

#define B_  2
#define CK_ 64
#define NM_ 32768
#define NQ_ 4096
#define CV_ 256
#define K_  20
#define SEG2_ 8      // m-segments; thread-pair halves -> 16 partitions
#define PARTS_ 16
#define CHUNKS_ 128  // 32-m chunks per segment

typedef unsigned short ushort_t;
typedef unsigned int uint_t;
typedef unsigned long long u64_t;
typedef float f32x4 __attribute__((ext_vector_type(4)));
typedef float f32x16 __attribute__((ext_vector_type(16)));
typedef short short8v __attribute__((ext_vector_type(8)));

__device__ __forceinline__ ushort_t f2bf_rn(float f) {
  uint_t x = __float_as_uint(f);
  uint_t r = x + 0x7FFFu + ((x >> 16) & 1u);
  return (ushort_t)(r >> 16);
}
__device__ __forceinline__ float bf2f(ushort_t u) {
  return __uint_as_float(((uint_t)u) << 16);
}

// ------------------------------------------------------------------
// prep_mk: mk[b][c][m] fp32 -> chunk-tiled bf16 hi/lo:
//   mkt/mlt layout: [b][gch(1024)][c8(8)][m&31(32)][8 bf16]  (granule = 16B)
//   where c8 = ks*2+hi covers channels c = c8*8 .. c8*8+7
__global__ __launch_bounds__(256) void prep_mk(const float* __restrict__ mk,
                                               ushort_t* __restrict__ mkt,
                                               ushort_t* __restrict__ mlt,
                                               float* __restrict__ ans) {
  int i = blockIdx.x * 256 + threadIdx.x;
  int b = i >> 15, m = i & (NM_ - 1);
  const float* src = mk + (size_t)b * CK_ * NM_ + m;
  const size_t chbase = ((size_t)(b * 1024 + (m >> 5)) << 11);
  const int ml = m & 31;
  float s = 0.f;
  #pragma unroll
  for (int c8 = 0; c8 < 8; ++c8) {
    ushort_t hh[8], ll[8];
    #pragma unroll
    for (int j = 0; j < 8; ++j) {
      float v = src[(size_t)(c8 * 8 + j) * NM_];
      s = fmaf(v, v, s);
      ushort_t h = f2bf_rn(v);
      hh[j] = h;
      ll[j] = f2bf_rn(v - bf2f(h));
    }
    size_t off = chbase + (c8 << 8) + (ml << 3);
    *reinterpret_cast<short8v*>(mkt + off) = *reinterpret_cast<short8v*>(hh);
    *reinterpret_cast<short8v*>(mlt + off) = *reinterpret_cast<short8v*>(ll);
  }
  ans[i] = 0.125f * s;
}

// prep_qk: qk[b][c][q] fp32 -> qkh/qkl[b][q][c] bf16 split of 0.25*qk
__global__ __launch_bounds__(256) void prep_qk(const float* __restrict__ qk,
                                               ushort_t* __restrict__ qkh,
                                               ushort_t* __restrict__ qkl) {
  int i = blockIdx.x * 256 + threadIdx.x;
  int b = i >> 12, q = i & (NQ_ - 1);
  const float* src = qk + (size_t)b * CK_ * NQ_ + q;
  ushort_t* dh = qkh + (size_t)i * CK_;
  ushort_t* dl = qkl + (size_t)i * CK_;
  #pragma unroll
  for (int c8 = 0; c8 < 8; ++c8) {
    ushort_t hh[8], ll[8];
    #pragma unroll
    for (int j = 0; j < 8; ++j) {
      float v = 0.25f * src[(size_t)(c8 * 8 + j) * NQ_];
      ushort_t h = f2bf_rn(v);
      hh[j] = h;
      ll[j] = f2bf_rn(v - bf2f(h));
    }
    *reinterpret_cast<short8v*>(dh + c8 * 8) = *reinterpret_cast<short8v*>(hh);
    *reinterpret_cast<short8v*>(dl + c8 * 8) = *reinterpret_cast<short8v*>(ll);
  }
}

// ------------------------------------------------------------------
__global__ __launch_bounds__(256) void transpose_mv(const float* __restrict__ mv0,
                                                    const float* __restrict__ mv1,
                                                    ushort_t* __restrict__ mvt0,
                                                    ushort_t* __restrict__ mvt1) {
  __shared__ float tl[64][33];
  const int zz = blockIdx.z;
  const int bank = zz & 1, b = zz >> 1;
  const float* src = (bank ? mv1 : mv0) + (size_t)b * CV_ * NM_;
  ushort_t*    dst = (bank ? mvt1 : mvt0) + (size_t)b * NM_ * CV_;
  const int m0 = blockIdx.x * 32, c0 = blockIdx.y * 64;
  const int t = threadIdx.x;
  #pragma unroll
  for (int i = 0; i < 8; ++i) {
    int f = t + 256 * i;
    int c = f >> 5, ml = f & 31;
    tl[c][ml] = src[(size_t)(c0 + c) * NM_ + m0 + ml];
  }
  __syncthreads();
  int m = t >> 3, c8 = t & 7;
  ushort_t pack[8];
  #pragma unroll
  for (int j = 0; j < 8; ++j) pack[j] = f2bf_rn(tl[c8 * 8 + j][m]);
  *reinterpret_cast<short8v*>(dst + (size_t)(m0 + m) * CV_ + c0 + c8 * 8) =
      *reinterpret_cast<short8v*>(pack);
}

// ------------------------------------------------------------------
// exact fp32 top-20: named scalar pairs, fmax/fmin + cndmask ripple
#define TKF_FOR(F) F(0) F(1) F(2) F(3) F(4) F(5) F(6) F(7) F(8) F(9) F(10) F(11) F(12) F(13) F(14) F(15) F(16) F(17) F(18) F(19)
#define TKF_DECL(J) float tv##J = -3.4e38f; int ti##J = 0;

#define TKF_SW(A,B) { bool c_ = tv##B > tv##A; \
  float fx_ = fmaxf(tv##A, tv##B); float fn_ = fminf(tv##A, tv##B); \
  int ix_ = c_ ? ti##B : ti##A;    int in_ = c_ ? ti##A : ti##B; \
  tv##A = fx_; tv##B = fn_; ti##A = ix_; ti##B = in_; }

#define TKF_INS(S,M) { if ((S) > tv19) { tv19 = (S); ti19 = (M); \
  TKF_SW(18,19) TKF_SW(17,18) TKF_SW(16,17) TKF_SW(15,16) TKF_SW(14,15) \
  TKF_SW(13,14) TKF_SW(12,13) TKF_SW(11,12) TKF_SW(10,11) TKF_SW(9,10) \
  TKF_SW(8,9) TKF_SW(7,8) TKF_SW(6,7) TKF_SW(5,6) TKF_SW(4,5) \
  TKF_SW(3,4) TKF_SW(2,3) TKF_SW(1,2) TKF_SW(0,1) } }

#define TKF_PUSH(S,M) { float s_ = (S); if (s_ > tv19) { \
  caf5 = caf4; cam5 = cam4; caf4 = caf3; cam4 = cam3; caf3 = caf2; cam3 = cam2; \
  caf2 = caf1; cam2 = cam1; caf1 = caf0; cam1 = cam0; caf0 = s_; cam0 = (M); ++cnt; } }

#define TKD_ONE(J) { float sd_ = (cnt > (J)) ? caf##J : -3.4e38f; int md_ = cam##J; TKF_INS(sd_, md_) }
#define TKF_DRAIN() { TKD_ONE(0) TKD_ONE(1) TKD_ONE(2) TKD_ONE(3) TKD_ONE(4) TKD_ONE(5) cnt = 0; }
#define TKF_CHK() { if (__any(cnt >= 3)) { TKF_DRAIN() } }

#define MFMA32(A,B,C) __builtin_amdgcn_mfma_f32_32x32x16_bf16((A),(B),(C),0,0,0)

#define GLOAD_LDS16(G, L) __builtin_amdgcn_global_load_lds( \
    (__attribute__((address_space(1))) unsigned int*)(G), \
    (__attribute__((address_space(3))) unsigned int*)(L), 16, 0, 0)

// score + exact top-20. block = 256 thr (4 waves) = 128 queries (2 thr/query).
// grid: (NQ/128, SEG2_, B). A staged via LDS double-buffer (global_load_lds).
__global__ __launch_bounds__(256, 2) void score_topk_mfma(
    const ushort_t* __restrict__ mkt, const ushort_t* __restrict__ mlt,
    const ushort_t* __restrict__ qkh, const ushort_t* __restrict__ qkl,
    const float* __restrict__ ans,
    float* __restrict__ pvals, int* __restrict__ pidx) {
  __shared__ __attribute__((aligned(16))) ushort_t ldsH[2 * 2048];
  __shared__ __attribute__((aligned(16))) ushort_t ldsL[2 * 2048];
  __shared__ __attribute__((aligned(16))) float    ldsA[2 * 32];
  const int t = threadIdx.x;
  const int b = blockIdx.z, seg = blockIdx.y, qblk = blockIdx.x;
  const int w = t >> 6, l = t & 63;
  const int lq = l & 31, hi = l >> 5;
  const int q = qblk * 128 + w * 32 + lq;
  const int gch0 = seg * CHUNKS_;

  // persistent B fragments (qk hi + lo)
  const size_t qbase = (((size_t)b * NQ_ + q) << 6) + hi * 8;
  const short8v bh0 = *(const short8v*)(qkh + qbase);
  const short8v bh1 = *(const short8v*)(qkh + qbase + 16);
  const short8v bh2 = *(const short8v*)(qkh + qbase + 32);
  const short8v bh3 = *(const short8v*)(qkh + qbase + 48);
  const short8v bl0 = *(const short8v*)(qkl + qbase);
  const short8v bl1 = *(const short8v*)(qkl + qbase + 16);
  const short8v bl2 = *(const short8v*)(qkl + qbase + 32);
  const short8v bl3 = *(const short8v*)(qkl + qbase + 48);

  TKF_FOR(TKF_DECL)
  float caf0 = 0, caf1 = 0, caf2 = 0, caf3 = 0, caf4 = 0, caf5 = 0;
  int cam0 = 0, cam1 = 0, cam2 = 0, cam3 = 0, cam4 = 0, cam5 = 0;
  int cnt = 0;

#define STAGE(NBUF, GCH) { \
  const size_t cb_ = ((size_t)(b * 1024) + (GCH)) << 11; \
  GLOAD_LDS16(mkt + cb_ + (((w << 6) + l) << 3), &ldsH[(NBUF) * 2048 + (w << 9)]); \
  GLOAD_LDS16(mlt + cb_ + (((w << 6) + l) << 3), &ldsL[(NBUF) * 2048 + (w << 9)]); \
  if (t < 8) GLOAD_LDS16(ans + ((size_t)b << 15) + ((GCH) << 5) + (t << 2), &ldsA[(NBUF) * 32]); \
}

#define ITER(CH, BUF) { \
  int chn_ = (CH) + 1; if (chn_ > CHUNKS_ - 1) chn_ = CHUNKS_ - 1; \
  STAGE(1 - (BUF), gch0 + chn_) \
  const int fro_ = (BUF) * 2048 + (hi << 8) + (lq << 3); \
  const short8v ah0 = *(const short8v*)&ldsH[fro_ + 0 * 512]; \
  const short8v ah1 = *(const short8v*)&ldsH[fro_ + 1 * 512]; \
  const short8v ah2 = *(const short8v*)&ldsH[fro_ + 2 * 512]; \
  const short8v ah3 = *(const short8v*)&ldsH[fro_ + 3 * 512]; \
  const short8v al0 = *(const short8v*)&ldsL[fro_ + 0 * 512]; \
  const short8v al1 = *(const short8v*)&ldsL[fro_ + 1 * 512]; \
  const short8v al2 = *(const short8v*)&ldsL[fro_ + 2 * 512]; \
  const short8v al3 = *(const short8v*)&ldsL[fro_ + 3 * 512]; \
  const float* ap_ = &ldsA[(BUF) * 32 + (hi << 2)]; \
  f32x4 an_a = *(const f32x4*)ap_; \
  f32x4 an_b = *(const f32x4*)(ap_ + 8); \
  f32x4 an_c = *(const f32x4*)(ap_ + 16); \
  f32x4 an_d = *(const f32x4*)(ap_ + 24); \
  f32x16 acc; \
  acc[0]  = -an_a[0]; acc[1]  = -an_a[1]; acc[2]  = -an_a[2]; acc[3]  = -an_a[3]; \
  acc[4]  = -an_b[0]; acc[5]  = -an_b[1]; acc[6]  = -an_b[2]; acc[7]  = -an_b[3]; \
  acc[8]  = -an_c[0]; acc[9]  = -an_c[1]; acc[10] = -an_c[2]; acc[11] = -an_c[3]; \
  acc[12] = -an_d[0]; acc[13] = -an_d[1]; acc[14] = -an_d[2]; acc[15] = -an_d[3]; \
  acc = MFMA32(ah0, bh0, acc); \
  acc = MFMA32(ah1, bh1, acc); \
  acc = MFMA32(ah2, bh2, acc); \
  acc = MFMA32(ah3, bh3, acc); \
  acc = MFMA32(ah0, bl0, acc); \
  acc = MFMA32(ah1, bl1, acc); \
  acc = MFMA32(ah2, bl2, acc); \
  acc = MFMA32(ah3, bl3, acc); \
  acc = MFMA32(al0, bh0, acc); \
  acc = MFMA32(al1, bh1, acc); \
  acc = MFMA32(al2, bh2, acc); \
  acc = MFMA32(al3, bh3, acc); \
  const int mb = ((gch0 + (CH)) << 5) + (hi << 2); \
  TKF_PUSH(acc[0], mb + 0)  TKF_PUSH(acc[1], mb + 1)  TKF_PUSH(acc[2], mb + 2)  TKF_PUSH(acc[3], mb + 3)  TKF_CHK() \
  TKF_PUSH(acc[4], mb + 8)  TKF_PUSH(acc[5], mb + 9)  TKF_PUSH(acc[6], mb + 10) TKF_PUSH(acc[7], mb + 11) TKF_CHK() \
  TKF_PUSH(acc[8], mb + 16) TKF_PUSH(acc[9], mb + 17) TKF_PUSH(acc[10],mb + 18) TKF_PUSH(acc[11],mb + 19) TKF_CHK() \
  TKF_PUSH(acc[12],mb + 24) TKF_PUSH(acc[13],mb + 25) TKF_PUSH(acc[14],mb + 26) TKF_PUSH(acc[15],mb + 27) TKF_CHK() \
  __syncthreads(); \
}

  // prologue: stage chunk 0 into buf 0
  STAGE(0, gch0)
  __syncthreads();

  #pragma clang loop unroll(disable)
  for (int ch2 = 0; ch2 < CHUNKS_ / 2; ++ch2) {
    const int ch = ch2 * 2;
    ITER(ch, 0)
    ITER(ch + 1, 1)
  }
  if (__any(cnt > 0)) { TKF_DRAIN() }

#undef ITER
#undef STAGE

  const int part = (seg << 1) + hi;
  float* pv = pvals + (((size_t)((b * PARTS_ + part) * K_)) << 12) + q;
  int*   pi = pidx  + (((size_t)((b * PARTS_ + part) * K_)) << 12) + q;
#define TKF_STORE(J) { pv[(size_t)(J) << 12] = tv##J; pi[(size_t)(J) << 12] = ti##J; }
  TKF_FOR(TKF_STORE)
#undef TKF_STORE
}

// ------------------------------------------------------------------
__global__ __launch_bounds__(256) void merge_kernel(const float* __restrict__ pvals,
                                                    const int* __restrict__ pidx,
                                                    float* __restrict__ fw,
                                                    int* __restrict__ fidx, int S) {
  int i = blockIdx.x * 256 + threadIdx.x;
  int b = i >> 12, q = i & (NQ_ - 1);

  float vals[K_]; int idxs[K_];
  #pragma unroll
  for (int j = 0; j < K_; ++j) { vals[j] = -3.4e38f; idxs[j] = 0; }

  for (int seg = 0; seg < S; ++seg) {
    #pragma unroll
    for (int j = 0; j < K_; ++j) {
      size_t o = (size_t)((b * S + seg) * K_ + j) * NQ_ + q;
      float v = pvals[o];
      if (v > vals[K_ - 1]) {
        int m = pidx[o];
        vals[K_ - 1] = v; idxs[K_ - 1] = m;
        #pragma unroll
        for (int jj = K_ - 1; jj > 0; --jj) {
          if (vals[jj] > vals[jj - 1]) {
            float tv = vals[jj]; vals[jj] = vals[jj - 1]; vals[jj - 1] = tv;
            int   ti = idxs[jj]; idxs[jj] = idxs[jj - 1]; idxs[jj - 1] = ti;
          }
        }
      }
    }
  }

  float mx = vals[0];
  float w[K_]; float sum = 0.f;
  #pragma unroll
  for (int j = 0; j < K_; ++j) { w[j] = expf(vals[j] - mx); sum += w[j]; }
  float inv = 1.f / sum;
  #pragma unroll
  for (int j = 0; j < K_; ++j) {
    size_t o = (size_t)(b * K_ + j) * NQ_ + q;
    fw[o] = w[j] * inv; fidx[o] = idxs[j];
  }
}

// ------------------------------------------------------------------
__global__ __launch_bounds__(256) void readout_bf16(const ushort_t* __restrict__ mvt0,
                                                    const ushort_t* __restrict__ mvt1,
                                                    const float* __restrict__ fw,
                                                    const int* __restrict__ fidx,
                                                    float* __restrict__ out) {
  __shared__ float mw[16][K_];
  __shared__ int   mi[16][K_];
  __shared__ float ob0[256][17];
  __shared__ float ob1[256][17];
  const int t = threadIdx.x;
  const int b = blockIdx.y;
  const int q0 = blockIdx.x * 16;

  for (int i = t; i < 16 * K_; i += 256) {
    int qp = i / K_, k = i % K_;
    size_t o = (size_t)(b * K_ + k) * NQ_ + q0 + qp;
    mw[qp][k] = fw[o];
    mi[qp][k] = fidx[o];
  }
  __syncthreads();

  const int c2 = (t & 127) * 2, hq = t >> 7;
  for (int qp = hq * 8; qp < hq * 8 + 8; ++qp) {
    float a00 = 0.f, a01 = 0.f, a10 = 0.f, a11 = 0.f;
    #pragma unroll 5
    for (int k = 0; k < K_; ++k) {
      int m = mi[qp][k]; float ww = mw[qp][k];
      size_t o = ((size_t)(b * NM_ + m) << 8) + c2;
      uint_t v0 = *reinterpret_cast<const uint_t*>(mvt0 + o);
      uint_t v1 = *reinterpret_cast<const uint_t*>(mvt1 + o);
      a00 = fmaf(ww, __uint_as_float(v0 << 16), a00);
      a01 = fmaf(ww, __uint_as_float(v0 & 0xFFFF0000u), a01);
      a10 = fmaf(ww, __uint_as_float(v1 << 16), a10);
      a11 = fmaf(ww, __uint_as_float(v1 & 0xFFFF0000u), a11);
    }
    ob0[c2][qp] = a00; ob0[c2 + 1][qp] = a01;
    ob1[c2][qp] = a10; ob1[c2 + 1][qp] = a11;
  }
  __syncthreads();

  float* out0 = out + (size_t)b * CV_ * NQ_;
  float* out1 = out + (size_t)B_ * CV_ * NQ_ + (size_t)b * CV_ * NQ_;
  for (int i = t; i < 256 * 16; i += 256) {
    int c = i >> 4, qp = i & 15;
    out0[(size_t)c * NQ_ + q0 + qp] = ob0[c][qp];
    out1[(size_t)c * NQ_ + q0 + qp] = ob1[c][qp];
  }
}

__global__ __launch_bounds__(256) void readout_f32(const float* __restrict__ v0src,
                                                   const float* __restrict__ v1src,
                                                   const float* __restrict__ fw,
                                                   const int* __restrict__ fidx,
                                                   float* __restrict__ out) {
  __shared__ float mw[16][K_];
  __shared__ int   mi[16][K_];
  __shared__ float ob0[256][17];
  __shared__ float ob1[256][17];
  const int t = threadIdx.x;
  const int b = blockIdx.y;
  const int q0 = blockIdx.x * 16;

  for (int i = t; i < 16 * K_; i += 256) {
    int qp = i / K_, k = i % K_;
    size_t o = (size_t)(b * K_ + k) * NQ_ + q0 + qp;
    mw[qp][k] = fw[o];
    mi[qp][k] = fidx[o];
  }
  __syncthreads();

  for (int qp = 0; qp < 16; ++qp) {
    float a0 = 0.f, a1 = 0.f;
    #pragma unroll 5
    for (int k = 0; k < K_; ++k) {
      int m = mi[qp][k]; float ww = mw[qp][k];
      size_t o = (size_t)b * CV_ * NM_ + (size_t)t * NM_ + m;
      a0 = fmaf(ww, v0src[o], a0);
      a1 = fmaf(ww, v1src[o], a1);
    }
    ob0[t][qp] = a0; ob1[t][qp] = a1;
  }
  __syncthreads();

  float* out0 = out + (size_t)b * CV_ * NQ_;
  float* out1 = out + (size_t)B_ * CV_ * NQ_ + (size_t)b * CV_ * NQ_;
  for (int i = t; i < 256 * 16; i += 256) {
    int c = i >> 4, qp = i & 15;
    out0[(size_t)c * NQ_ + q0 + qp] = ob0[c][qp];
    out1[(size_t)c * NQ_ + q0 + qp] = ob1[c][qp];
  }
}

// ------------------------------------------------------------------
extern "C" void kernel_launch(void* const* d_in, const int* in_sizes, int n_in,
                              void* d_out, int out_size, void* d_ws, size_t ws_size,
                              hipStream_t stream) {
  (void)in_sizes; (void)n_in; (void)out_size;
  const float* mk  = (const float*)d_in[0];
  const float* qk  = (const float*)d_in[1];
  const float* mv0 = (const float*)d_in[2];
  const float* mv1 = (const float*)d_in[3];
  float* out = (float*)d_out;

  auto al = [](size_t x) { return (x + 255) & ~(size_t)255; };
  const size_t mkB  = (size_t)B_ * NM_ * CK_ * 2;
  const size_t qkB  = (size_t)B_ * NQ_ * CK_ * 2;
  const size_t anB  = (size_t)B_ * NM_ * 4;
  const size_t prtB = (size_t)B_ * PARTS_ * K_ * NQ_ * 4;
  const size_t finB = (size_t)B_ * K_ * NQ_ * 4;
  const size_t tpB  = (size_t)B_ * NM_ * CV_ * 2;

  const size_t core = 2 * al(mkB) + 2 * al(qkB) + al(anB) + 2 * al(prtB) + 2 * al(finB);
  const bool tp = ws_size >= core + 2 * al(tpB);

  char* p = (char*)d_ws;
  ushort_t* mkt = (ushort_t*)p; p += al(mkB);
  ushort_t* mlt = (ushort_t*)p; p += al(mkB);
  ushort_t* qkh = (ushort_t*)p; p += al(qkB);
  ushort_t* qkl = (ushort_t*)p; p += al(qkB);
  float* ans    = (float*)p;    p += al(anB);
  float* pvals  = (float*)p;    p += al(prtB);
  int*   pidx   = (int*)p;      p += al(prtB);
  float* fw     = (float*)p;    p += al(finB);
  int*   fidx   = (int*)p;      p += al(finB);
  ushort_t* mvt0 = nullptr, * mvt1 = nullptr;
  if (tp) { mvt0 = (ushort_t*)p; p += al(tpB); mvt1 = (ushort_t*)p; p += al(tpB); }

  prep_mk<<<B_ * NM_ / 256, 256, 0, stream>>>(mk, mkt, mlt, ans);
  prep_qk<<<B_ * NQ_ / 256, 256, 0, stream>>>(qk, qkh, qkl);
  if (tp)
    transpose_mv<<<dim3(NM_ / 32, CV_ / 64, B_ * 2), 256, 0, stream>>>(mv0, mv1, mvt0, mvt1);
  score_topk_mfma<<<dim3(NQ_ / 128, SEG2_, B_), 256, 0, stream>>>(mkt, mlt, qkh, qkl, ans, pvals, pidx);
  merge_kernel<<<B_ * NQ_ / 256, 256, 0, stream>>>(pvals, pidx, fw, fidx, PARTS_);
  if (tp) readout_bf16<<<dim3(NQ_ / 16, B_), 256, 0, stream>>>(mvt0, mvt1, fw, fidx, out);
  else    readout_f32<<<dim3(NQ_ / 16, B_), 256, 0, stream>>>(mv0, mv1, fw, fidx, out);
}